// Round 1
// baseline (1603.690 us; speedup 1.0000x reference)
//
#include <hip/hip_runtime.h>
#include <hip/hip_bf16.h>

// EdgeModel: out = relu(concat(src,dest,edge_attr,u[batch]) @ W1 + b1) @ W2 + b2
// E=500000, F_IN=35 (pad->64), H=512, OUT=512. Fused one-pass kernel, bf16 MFMA.

#define E_TOTAL   500000
#define H_SZ      512
#define OUT_SZ    512
#define K1        64        // layer-1 K padded 35 -> 64 (zeros both sides)
#define MT        64        // edges per block
#define XS_PAD    72        // x-tile row stride (bf16 elems): 36 words -> 2-way bank (free)

typedef __attribute__((ext_vector_type(8))) short bf16x8;   // 8 bf16 = 4 VGPRs
typedef __attribute__((ext_vector_type(4))) float f32x4;    // MFMA 16x16 acc

union V8 { bf16x8 v; unsigned short s[8]; };

static __device__ __forceinline__ unsigned short f2b(float f) {
    __hip_bfloat16 h = __float2bfloat16(f);   // RNE
    return *reinterpret_cast<unsigned short*>(&h);
}

// h tile [64][512] bf16, XOR-swizzled 16B units so LDS stays exactly 64 KB
// (no +pad) while m-strided b128 reads are 2-way (free) instead of 16-way.
static __device__ __forceinline__ int hidx(int m, int k) {
    int ku = (k >> 3) ^ (m & 7);
    return (m << 9) + (ku << 3) + (k & 7);
}

// ---- prep: bf16 weight repack into ws ----
// W2t[n][k] = bf16(W2[k][n])  (512x512)
// W1t[n][k] = bf16(k<35 ? W1[k][n] : 0)  (512x64)
__global__ __launch_bounds__(256) void prep_weights(
        const float* __restrict__ W1, const float* __restrict__ W2,
        unsigned short* __restrict__ W2t, unsigned short* __restrict__ W1t) {
    int t = blockIdx.x * 256 + threadIdx.x;
    const int total2 = H_SZ * OUT_SZ;           // 262144
    if (t < total2) {
        int k = t >> 9, n = t & 511;            // coalesced read over n
        W2t[n * H_SZ + k] = f2b(W2[k * OUT_SZ + n]);
    } else {
        int t1 = t - total2;
        if (t1 < K1 * 512) {                    // 32768
            int k = t1 >> 9, n = t1 & 511;
            float v = (k < 35) ? W1[k * H_SZ + n] : 0.0f;
            W1t[n * K1 + k] = f2b(v);
        }
    }
}

__global__ __launch_bounds__(512) void edge_mlp(
        const float* __restrict__ gsrc, const float* __restrict__ gdst,
        const float* __restrict__ gea,  const float* __restrict__ gu,
        const int* __restrict__ gbatch,
        const float* __restrict__ b1,   const float* __restrict__ b2,
        const unsigned short* __restrict__ W1t,
        const unsigned short* __restrict__ W2t,
        float* __restrict__ out) {

    __shared__ unsigned short hs[MT * 512];     // 65536 B exactly
    unsigned short* xs = hs;                    // x tile aliases hs; dead before hs written

    const int tid  = threadIdx.x;
    const int e0   = blockIdx.x * MT;
    const int l    = tid & 63;
    const int w    = tid >> 6;                  // wave 0..7, owns cols [w*64, w*64+64)
    const int l15  = l & 15;
    const int quad = l >> 4;

    // ---- stage x tile: 8 threads per edge, 8 features each -> xs[64][72] bf16 ----
    {
        const int el = tid >> 3;
        const int s  = tid & 7;
        const int c0 = s << 3;
        const int e  = e0 + el;
        V8 vv;
        if (e < E_TOTAL) {
            const int b = gbatch[e] & 1023;
            #pragma unroll
            for (int j = 0; j < 8; ++j) {
                const int c = c0 + j;
                float v;
                if      (c < 9)   v = gsrc[e * 9 + c];
                else if (c < 18)  v = gdst[e * 9 + (c - 9)];
                else if (c == 18) v = gea[e];
                else if (c < 35)  v = gu[(b << 4) + (c - 19)];
                else              v = 0.0f;       // K padding must be zero
                vv.s[j] = f2b(v);
            }
        } else {
            #pragma unroll
            for (int j = 0; j < 8; ++j) vv.s[j] = 0;
        }
        *reinterpret_cast<bf16x8*>(&xs[el * XS_PAD + c0]) = vv.v;   // ds_write_b128
    }
    __syncthreads();

    f32x4 acc[4][4];
    #pragma unroll
    for (int mi = 0; mi < 4; ++mi)
        #pragma unroll
        for (int ni = 0; ni < 4; ++ni)
            acc[mi][ni] = (f32x4){0.f, 0.f, 0.f, 0.f};

    // ---- layer 1: h[0:64, w*64 : w*64+64] = x[64,64] @ W1t^T, K=64 -> 2 ksteps ----
    #pragma unroll
    for (int ks = 0; ks < 2; ++ks) {
        bf16x8 afr[4], bfr[4];
        #pragma unroll
        for (int mi = 0; mi < 4; ++mi)
            afr[mi] = *reinterpret_cast<const bf16x8*>(
                &xs[(mi * 16 + l15) * XS_PAD + ks * 32 + quad * 8]);
        #pragma unroll
        for (int ni = 0; ni < 4; ++ni)
            bfr[ni] = *reinterpret_cast<const bf16x8*>(
                &W1t[(w * 64 + ni * 16 + l15) * K1 + ks * 32 + quad * 8]);
        #pragma unroll
        for (int mi = 0; mi < 4; ++mi)
            #pragma unroll
            for (int ni = 0; ni < 4; ++ni)
                acc[mi][ni] = __builtin_amdgcn_mfma_f32_16x16x32_bf16(
                    afr[mi], bfr[ni], acc[mi][ni], 0, 0, 0);
    }
    __syncthreads();    // all xs reads complete before hs overwrite

    // ---- bias + relu -> bf16 h tile in LDS (C-layout: row=quad*4+r, col=l15) ----
    #pragma unroll
    for (int ni = 0; ni < 4; ++ni) {
        const int col = w * 64 + ni * 16 + l15;
        const float bv = b1[col];
        #pragma unroll
        for (int mi = 0; mi < 4; ++mi)
            #pragma unroll
            for (int r = 0; r < 4; ++r) {
                const int row = mi * 16 + quad * 4 + r;
                const float v = acc[mi][ni][r] + bv;
                hs[hidx(row, col)] = f2b(v > 0.f ? v : 0.f);
            }
    }
    __syncthreads();

    // ---- layer 2: out[64, w*64:+64] = h[64,512] @ W2t^T, 16 ksteps ----
    #pragma unroll
    for (int mi = 0; mi < 4; ++mi)
        #pragma unroll
        for (int ni = 0; ni < 4; ++ni)
            acc[mi][ni] = (f32x4){0.f, 0.f, 0.f, 0.f};

    const unsigned short* w2p = W2t + (w * 64 + l15) * H_SZ + quad * 8;

    #pragma unroll 4
    for (int k0 = 0; k0 < 16; ++k0) {
        bf16x8 afr[4], bfr[4];
        const int kk = k0 * 32 + quad * 8;
        #pragma unroll
        for (int mi = 0; mi < 4; ++mi)
            afr[mi] = *reinterpret_cast<const bf16x8*>(&hs[hidx(mi * 16 + l15, kk)]);
        #pragma unroll
        for (int ni = 0; ni < 4; ++ni)
            bfr[ni] = *reinterpret_cast<const bf16x8*>(&w2p[ni * (16 * H_SZ) + k0 * 32]);
        #pragma unroll
        for (int mi = 0; mi < 4; ++mi)
            #pragma unroll
            for (int ni = 0; ni < 4; ++ni)
                acc[mi][ni] = __builtin_amdgcn_mfma_f32_16x16x32_bf16(
                    afr[mi], bfr[ni], acc[mi][ni], 0, 0, 0);
    }

    // ---- epilogue: + b2, f32 store ----
    #pragma unroll
    for (int ni = 0; ni < 4; ++ni) {
        const int col = w * 64 + ni * 16 + l15;
        const float bv = b2[col];
        #pragma unroll
        for (int mi = 0; mi < 4; ++mi)
            #pragma unroll
            for (int r = 0; r < 4; ++r) {
                const int e = e0 + mi * 16 + quad * 4 + r;
                if (e < E_TOTAL)
                    out[(size_t)e * OUT_SZ + col] = acc[mi][ni][r] + bv;
            }
    }
}

extern "C" void kernel_launch(void* const* d_in, const int* in_sizes, int n_in,
                              void* d_out, int out_size, void* d_ws, size_t ws_size,
                              hipStream_t stream) {
    const float* src   = (const float*)d_in[0];
    const float* dst   = (const float*)d_in[1];
    const float* eattr = (const float*)d_in[2];
    const float* u     = (const float*)d_in[3];
    const int*   batch = (const int*)d_in[4];
    const float* W1    = (const float*)d_in[5];
    const float* b1    = (const float*)d_in[6];
    const float* W2    = (const float*)d_in[7];
    const float* b2    = (const float*)d_in[8];
    float* out = (float*)d_out;

    // ws layout: W2t (512*512 bf16 = 512 KB) | W1t (512*64 bf16 = 64 KB)
    unsigned short* W2t = (unsigned short*)d_ws;
    unsigned short* W1t = W2t + H_SZ * OUT_SZ;

    const int prep_total = H_SZ * OUT_SZ + 512 * K1;        // 294912
    prep_weights<<<(prep_total + 255) / 256, 256, 0, stream>>>(W1, W2, W2t, W1t);

    const int nblk = (E_TOTAL + MT - 1) / MT;               // 7813
    edge_mlp<<<nblk, 512, 0, stream>>>(src, dst, eattr, u, batch,
                                       b1, b2, W1t, W2t, out);
}